// Round 1
// baseline (142.488 us; speedup 1.0000x reference)
//
#include <hip/hip_runtime.h>
#include <math.h>

typedef float f32x4 __attribute__((ext_vector_type(4)));
typedef short s16x8 __attribute__((ext_vector_type(8)));

#define N_NODES 2048
#define KEDGE 32
#define HDIM 128
#define FDIM 512

__device__ __forceinline__ short f2bf(float f){
  unsigned u = __builtin_bit_cast(unsigned, f);
  u += 0x7fffu + ((u >> 16) & 1u);
  return (short)(u >> 16);
}

__device__ __forceinline__ void gld16(const void* g, void* l){
  __builtin_amdgcn_global_load_lds(
      (const __attribute__((address_space(1))) void*)g,
      (__attribute__((address_space(3))) void*)l, 16, 0, 0);
}

// Pack W1 (512x128) and W2 (128x128) fp32 -> bf16 in MFMA B-fragment order:
// elem((ks,ct,lane,j)) = W[ks*32 + (lane>>4)*8 + j][ct*16 + (lane&15)]
__global__ void pack_w(const float* __restrict__ W1, const float* __restrict__ W2,
                       short* __restrict__ W1f, short* __restrict__ W2f){
  int t = blockIdx.x * 256 + threadIdx.x;
  if (t < 65536){
    int ks = t >> 12, r = t & 4095;
    int ct = r >> 9;  r &= 511;
    int lane = r >> 3, j = r & 7;
    int k = ks*32 + (lane>>4)*8 + j;
    int n = ct*16 + (lane&15);
    W1f[t] = f2bf(W1[k*128 + n]);
  } else if (t < 81920){
    int t2 = t - 65536;
    int ks = t2 >> 12, r = t2 & 4095;
    int ct = r >> 9;  r &= 511;
    int lane = r >> 3, j = r & 7;
    int k = ks*32 + (lane>>4)*8 + j;
    int n = ct*16 + (lane&15);
    W2f[t2] = f2bf(W2[k*128 + n]);
  }
}

// E_idx dtype detection: if stored as int64, every odd 32-bit word is 0.
__global__ void detect_init(unsigned* flag){
  if (blockIdx.x == 0 && threadIdx.x == 0) *flag = 0u;
}
__global__ void detect_idx(const unsigned* __restrict__ e, unsigned* flag){
  int t = blockIdx.x * 256 + threadIdx.x;          // t < 131072
  unsigned v = e[2*t + 1];                          // within 1 MB either way
  unsigned long long m = __ballot(v != 0u);
  if ((threadIdx.x & 63) == 0 && m) atomicOr(flag, 1u);
}

__global__ __launch_bounds__(256, 2)
void fused(const float* __restrict__ hS, const float* __restrict__ hV,
           const float* __restrict__ hE, const int* __restrict__ Eidx,
           const float* __restrict__ mask,
           const float* __restrict__ W1b, const float* __restrict__ W2b,
           const float* __restrict__ lng, const float* __restrict__ lnb,
           const short* __restrict__ W1f, const short* __restrict__ W2f,
           const unsigned* __restrict__ idx_flag,
           float* __restrict__ out)
{
  __shared__ short Bst[2][4096];   // double-buffered W1 k-step tile (8 KB each)
  __shared__ short hfr[4][4096];   // per-wave gelu(h1) in A-frag order (8 KB each)

  const int tid  = threadIdx.x;
  const int w    = tid >> 6;
  const int lane = tid & 63;
  const int l15  = lane & 15;
  const int lg   = lane >> 4;

  const int ng = blockIdx.x * 4 + w;     // global node id (= b*N + n)
  const int b  = ng >> 11;
  const long nodeoff = (long)ng * HDIM;
  const int  ebase   = ng * KEDGE;

  const int is64 = (*idx_flag == 0u);    // all odd words zero -> int64

  // per row-tile (rt=0,1) edge info: row = rt*16 + l15
  int eidx[2]; float mval[2];
  const float* segbase[4][2];
  #pragma unroll
  for (int rt = 0; rt < 2; ++rt){
    int e = ebase + rt*16 + l15;
    eidx[rt] = is64 ? Eidx[2*e] : Eidx[e];
    mval[rt] = mask[e];
    segbase[0][rt] = hV + nodeoff;
    segbase[1][rt] = hE + (long)e * 128;
    segbase[2][rt] = hS + (long)(b*N_NODES + eidx[rt]) * 128;
    segbase[3][rt] = hV + (long)(b*N_NODES + eidx[rt]) * 128;
  }

  // ---- GEMM1: [32 x 512] @ W1 -> acc1 [32 x 128] per wave ----
  f32x4 acc1[2][8];
  #pragma unroll
  for (int rt = 0; rt < 2; ++rt)
    #pragma unroll
    for (int ct = 0; ct < 8; ++ct)
      acc1[rt][ct] = (f32x4){0.f,0.f,0.f,0.f};

  auto loadA = [&](int ks, s16x8* af){
    const int seg = ks >> 2;
    const int off = (ks & 3)*32 + lg*8;
    #pragma unroll
    for (int rt = 0; rt < 2; ++rt){
      const float* p = segbase[seg][rt] + off;
      float4 x = *(const float4*)p;
      float4 y = *(const float4*)(p + 4);
      float sc = (seg == 0) ? 1.0f : mval[rt];
      s16x8 f;
      f[0]=f2bf(x.x*sc); f[1]=f2bf(x.y*sc); f[2]=f2bf(x.z*sc); f[3]=f2bf(x.w*sc);
      f[4]=f2bf(y.x*sc); f[5]=f2bf(y.y*sc); f[6]=f2bf(y.z*sc); f[7]=f2bf(y.w*sc);
      af[rt] = f;
    }
  };
  auto stageB = [&](int ks, int buf){
    const short* g0 = W1f + ks*4096 + (w*64 + lane)*8;
    gld16(g0,        &Bst[buf][(w*64)*8]);
    gld16(g0 + 2048, &Bst[buf][((w+4)*64)*8]);
  };

  s16x8 Acur[2], Anext[2];
  stageB(0, 0);
  loadA(0, Acur);
  for (int ks = 0; ks < 16; ++ks){
    __syncthreads();                       // staged tile ks now visible
    const int cur = ks & 1;
    if (ks < 15){ stageB(ks+1, cur^1); loadA(ks+1, Anext); }
    const short* bb = &Bst[cur][lane*8];
    #pragma unroll
    for (int ct = 0; ct < 8; ++ct){
      s16x8 bf = *(const s16x8*)(bb + ct*512);
      acc1[0][ct] = __builtin_amdgcn_mfma_f32_16x16x32_bf16(Acur[0], bf, acc1[0][ct], 0,0,0);
      acc1[1][ct] = __builtin_amdgcn_mfma_f32_16x16x32_bf16(Acur[1], bf, acc1[1][ct], 0,0,0);
    }
    if (ks < 15){ Acur[0] = Anext[0]; Acur[1] = Anext[1]; }
  }

  // ---- bias + exact GELU -> hfr (A-frag order) ----
  float b1[8];
  #pragma unroll
  for (int ct = 0; ct < 8; ++ct) b1[ct] = W1b[ct*16 + l15];

  short* hw = &hfr[w][0];
  #pragma unroll
  for (int rt = 0; rt < 2; ++rt)
    #pragma unroll
    for (int ct = 0; ct < 8; ++ct){
      const int ks2  = ct >> 1;
      const int laneP = lg*4 + 16*((ct&1)*2 + ((lane>>3)&1));
      const int j    = lane & 7;
      #pragma unroll
      for (int i = 0; i < 4; ++i){
        float x = acc1[rt][ct][i] + b1[ct];
        float g = 0.5f * x * (1.0f + erff(x * 0.70710678118f));
        hw[((rt*4 + ks2)*64 + (laneP + i))*8 + j] = f2bf(g);
      }
    }
  __syncthreads();

  // ---- GEMM2: [32 x 128] @ W2 -> acc2 [32 x 128] ----
  f32x4 acc2[2][8];
  #pragma unroll
  for (int rt = 0; rt < 2; ++rt)
    #pragma unroll
    for (int ct = 0; ct < 8; ++ct)
      acc2[rt][ct] = (f32x4){0.f,0.f,0.f,0.f};

  #pragma unroll
  for (int ks2 = 0; ks2 < 4; ++ks2){
    s16x8 a0 = *(const s16x8*)&hw[((0 + ks2)*64 + lane)*8];
    s16x8 a1 = *(const s16x8*)&hw[((4 + ks2)*64 + lane)*8];
    const short* wb = W2f + (ks2*8)*512 + lane*8;
    #pragma unroll
    for (int ct = 0; ct < 8; ++ct){
      s16x8 bf = *(const s16x8*)(wb + ct*512);
      acc2[0][ct] = __builtin_amdgcn_mfma_f32_16x16x32_bf16(a0, bf, acc2[0][ct], 0,0,0);
      acc2[1][ct] = __builtin_amdgcn_mfma_f32_16x16x32_bf16(a1, bf, acc2[1][ct], 0,0,0);
    }
  }

  // ---- reduce over 32 edges, + h_V, LayerNorm, store ----
  float res[8];
  float vsum = 0.f, vsq = 0.f;
  #pragma unroll
  for (int ct = 0; ct < 8; ++ct){
    float s = acc2[0][ct][0] + acc2[0][ct][1] + acc2[0][ct][2] + acc2[0][ct][3]
            + acc2[1][ct][0] + acc2[1][ct][1] + acc2[1][ct][2] + acc2[1][ct][3];
    s += __shfl_xor(s, 16, 64);
    s += __shfl_xor(s, 32, 64);
    const int c = ct*16 + l15;
    float dh = (s + 32.0f * W2b[c]) * (1.0f/30.0f);
    float val = hV[nodeoff + c] + dh;
    res[ct] = val;
    vsum += val; vsq += val*val;
  }
  vsum += __shfl_xor(vsum, 1, 64);  vsum += __shfl_xor(vsum, 2, 64);
  vsum += __shfl_xor(vsum, 4, 64);  vsum += __shfl_xor(vsum, 8, 64);
  vsq  += __shfl_xor(vsq, 1, 64);   vsq  += __shfl_xor(vsq, 2, 64);
  vsq  += __shfl_xor(vsq, 4, 64);   vsq  += __shfl_xor(vsq, 8, 64);
  const float mu  = vsum * (1.0f/128.0f);
  const float var = vsq * (1.0f/128.0f) - mu*mu;
  const float rs  = rsqrtf(var + 1e-5f);

  #pragma unroll
  for (int q = 0; q < 2; ++q){
    const int ct = lg*2 + q;
    const int c  = ct*16 + l15;
    out[nodeoff + c] = (res[ct] - mu) * rs * lng[c] + lnb[c];
  }
}

extern "C" void kernel_launch(void* const* d_in, const int* in_sizes, int n_in,
                              void* d_out, int out_size, void* d_ws, size_t ws_size,
                              hipStream_t stream) {
  const float* hS  = (const float*)d_in[0];
  const float* hV  = (const float*)d_in[1];
  const float* hE  = (const float*)d_in[2];
  const int*   Ei  = (const int*)d_in[3];
  const float* mk  = (const float*)d_in[4];
  const float* W1w = (const float*)d_in[5];
  const float* W1b = (const float*)d_in[6];
  const float* W2w = (const float*)d_in[7];
  const float* W2b = (const float*)d_in[8];
  const float* lng = (const float*)d_in[9];
  const float* lnb = (const float*)d_in[10];

  short* W1f = (short*)d_ws;                       // 65536 bf16 = 128 KB
  short* W2f = W1f + 65536;                        // 16384 bf16 = 32 KB
  unsigned* flag = (unsigned*)((char*)d_ws + 163840);

  pack_w<<<320, 256, 0, stream>>>(W1w, W2w, W1f, W2f);
  detect_init<<<1, 64, 0, stream>>>(flag);
  detect_idx<<<512, 256, 0, stream>>>((const unsigned*)Ei, flag);
  fused<<<2048, 256, 0, stream>>>(hS, hV, hE, Ei, mk, W1b, W2b, lng, lnb,
                                  W1f, W2f, flag, (float*)d_out);
}

// Round 3
// 111.905 us; speedup vs baseline: 1.2733x; 1.2733x over previous
//
#include <hip/hip_runtime.h>
#include <math.h>

typedef float f32x4 __attribute__((ext_vector_type(4)));
typedef short s16x8 __attribute__((ext_vector_type(8)));
typedef unsigned u32x4 __attribute__((ext_vector_type(4)));

#define N_NODES 2048
#define KEDGE 32
#define HDIM 128

__device__ __forceinline__ short f2bf(float f){
  unsigned u = __builtin_bit_cast(unsigned, f);
  u += 0x7fffu + ((u >> 16) & 1u);
  return (short)(u >> 16);
}

__device__ __forceinline__ unsigned cvt_pk_bf16(float a, float b){
  unsigned r;
  asm("v_cvt_pk_bf16_f32 %0, %1, %2" : "=v"(r) : "v"(a), "v"(b));
  return r;
}

// tanh-form GELU via exp2+rcp: gelu(x) = x * sigmoid(1.59577x + 0.0713548x^3)
// max abs error vs exact ~5e-4
__device__ __forceinline__ float fast_gelu(float x){
  float t = x * (-2.3022078f - 0.1029527f * x * x);  // = -log2e * z
  float e = __builtin_amdgcn_exp2f(t);               // exp(-z)
  return x * __builtin_amdgcn_rcpf(1.0f + e);
}

__device__ __forceinline__ void gld16(const void* g, void* l){
  __builtin_amdgcn_global_load_lds(
      (const __attribute__((address_space(1))) void*)g,
      (__attribute__((address_space(3))) void*)l, 16, 0, 0);
}

// Pack W1 (512x128) and W2 (128x128) fp32 -> bf16 in MFMA B-fragment order:
// elem((ks,ct,lane,j)) = W[ks*32 + (lane>>4)*8 + j][ct*16 + (lane&15)]
__global__ void pack_w(const float* __restrict__ W1, const float* __restrict__ W2,
                       short* __restrict__ W1f, short* __restrict__ W2f){
  int t = blockIdx.x * 256 + threadIdx.x;
  if (t < 65536){
    int ks = t >> 12, r = t & 4095;
    int ct = r >> 9;  r &= 511;
    int lane = r >> 3, j = r & 7;
    int k = ks*32 + (lane>>4)*8 + j;
    int n = ct*16 + (lane&15);
    W1f[t] = f2bf(W1[k*128 + n]);
  } else if (t < 81920){
    int t2 = t - 65536;
    int ks = t2 >> 12, r = t2 & 4095;
    int ct = r >> 9;  r &= 511;
    int lane = r >> 3, j = r & 7;
    int k = ks*32 + (lane>>4)*8 + j;
    int n = ct*16 + (lane&15);
    W2f[t2] = f2bf(W2[k*128 + n]);
  }
}

// E_idx dtype detection: if stored as int64, every odd 32-bit word is 0.
__global__ void detect_init(unsigned* flag){
  if (blockIdx.x == 0 && threadIdx.x == 0) *flag = 0u;
}
__global__ void detect_idx(const unsigned* __restrict__ e, unsigned* flag){
  int t = blockIdx.x * 256 + threadIdx.x;          // t < 131072
  unsigned v = e[2*t + 1];
  unsigned long long m = __ballot(v != 0u);
  if ((threadIdx.x & 63) == 0 && m) atomicOr(flag, 1u);
}

__global__ __launch_bounds__(256, 4)
void fused(const float* __restrict__ hS, const float* __restrict__ hV,
           const float* __restrict__ hE, const int* __restrict__ Eidx,
           const float* __restrict__ mask,
           const float* __restrict__ W1b, const float* __restrict__ W2b,
           const float* __restrict__ lng, const float* __restrict__ lnb,
           const short* __restrict__ W1f, const short* __restrict__ W2f,
           const unsigned* __restrict__ idx_flag,
           float* __restrict__ out)
{
  // 32 KB: W1 double-buffer (2 x 8192 shorts) during GEMM1;
  // first 512 shorts reused as per-wave v-broadcast after a barrier.
  __shared__ short smem[16384];

  const int tid  = threadIdx.x;
  const int w    = tid >> 6;
  const int lane = tid & 63;
  const int l15  = lane & 15;
  const int lg   = lane >> 4;

  const int ng = blockIdx.x * 4 + w;     // global node id (= b*N + n)
  const int b  = ng >> 11;
  const long nodeoff = (long)ng * HDIM;
  const int  ebase   = ng * KEDGE;

  const int is64 = (*idx_flag == 0u);    // all odd words zero -> int64

  // per row-tile (rt=0,1) edge info: row = rt*16 + l15
  float mval[2];
  const float* segbase[4][2];
  #pragma unroll
  for (int rt = 0; rt < 2; ++rt){
    int e = ebase + rt*16 + l15;
    int eidx = is64 ? Eidx[2*e] : Eidx[e];
    mval[rt] = mask[e];
    segbase[0][rt] = hV + nodeoff;
    segbase[1][rt] = hE + (long)e * 128;
    segbase[2][rt] = hS + (long)(b*N_NODES + eidx) * 128;
    segbase[3][rt] = hV + (long)(b*N_NODES + eidx) * 128;
  }

  // ---- GEMM1: [32 x 512] @ W1 -> acc1 [32 x 128] per wave ----
  f32x4 acc1[2][8];
  #pragma unroll
  for (int rt = 0; rt < 2; ++rt)
    #pragma unroll
    for (int ct = 0; ct < 8; ++ct)
      acc1[rt][ct] = (f32x4){0.f,0.f,0.f,0.f};

  auto loadA = [&](int ks, s16x8* af){
    const int seg = ks >> 2;
    const int off = (ks & 3)*32 + lg*8;
    #pragma unroll
    for (int rt = 0; rt < 2; ++rt){
      const float* p = segbase[seg][rt] + off;
      float4 x = *(const float4*)p;
      float4 y = *(const float4*)(p + 4);
      float sc = (seg == 0) ? 1.0f : mval[rt];
      u32x4 pk;
      pk[0] = cvt_pk_bf16(x.x*sc, x.y*sc);
      pk[1] = cvt_pk_bf16(x.z*sc, x.w*sc);
      pk[2] = cvt_pk_bf16(y.x*sc, y.y*sc);
      pk[3] = cvt_pk_bf16(y.z*sc, y.w*sc);
      af[rt] = __builtin_bit_cast(s16x8, pk);
    }
  };
  // stage k-steps {2t, 2t+1} (16 KB) into buf
  auto stageB = [&](int t, int buf){
    const short* g0 = W1f + t*8192 + (w*4)*512 + lane*8;
    short* l0 = smem + buf*8192 + (w*4)*512;
    #pragma unroll
    for (int q = 0; q < 4; ++q) gld16(g0 + q*512, l0 + q*512);
  };

  s16x8 Acur[2], Anext[2];
  stageB(0, 0);
  loadA(0, Acur);
  for (int t = 0; t < 8; ++t){
    __syncthreads();                       // staged tile t now visible
    const int cur = t & 1;
    if (t < 7) stageB(t+1, cur^1);
    // sub-step 0 (ks = 2t)
    loadA(2*t+1, Anext);
    {
      const short* bb = smem + cur*8192 + lane*8;
      #pragma unroll
      for (int ct = 0; ct < 8; ++ct){
        s16x8 bf = *(const s16x8*)(bb + ct*512);
        acc1[0][ct] = __builtin_amdgcn_mfma_f32_16x16x32_bf16(Acur[0], bf, acc1[0][ct], 0,0,0);
        acc1[1][ct] = __builtin_amdgcn_mfma_f32_16x16x32_bf16(Acur[1], bf, acc1[1][ct], 0,0,0);
      }
    }
    Acur[0] = Anext[0]; Acur[1] = Anext[1];
    // sub-step 1 (ks = 2t+1)
    if (t < 7) loadA(2*t+2, Anext);
    {
      const short* bb = smem + cur*8192 + 4096 + lane*8;
      #pragma unroll
      for (int ct = 0; ct < 8; ++ct){
        s16x8 bf = *(const s16x8*)(bb + ct*512);
        acc1[0][ct] = __builtin_amdgcn_mfma_f32_16x16x32_bf16(Acur[0], bf, acc1[0][ct], 0,0,0);
        acc1[1][ct] = __builtin_amdgcn_mfma_f32_16x16x32_bf16(Acur[1], bf, acc1[1][ct], 0,0,0);
      }
    }
    if (t < 7){ Acur[0] = Anext[0]; Acur[1] = Anext[1]; }
  }

  // ---- bias + GELU, then reduce over the 32 edges IN REGISTERS ----
  // (sum over rows commutes with GEMM2: dh = (sum_e gelu(h_e)) @ W2 + 32*b2)
  float b1v[8];
  #pragma unroll
  for (int ct = 0; ct < 8; ++ct) b1v[ct] = W1b[ct*16 + l15];

  float v8[8];
  #pragma unroll
  for (int ct = 0; ct < 8; ++ct){
    float s = 0.f;
    #pragma unroll
    for (int rt = 0; rt < 2; ++rt)
      #pragma unroll
      for (int i = 0; i < 4; ++i)
        s += fast_gelu(acc1[rt][ct][i] + b1v[ct]);
    s += __shfl_xor(s, 16, 64);
    s += __shfl_xor(s, 32, 64);            // replicated across lg; col = ct*16+l15
    v8[ct] = s;
  }

  __syncthreads();                          // all waves done reading W1 tiles

  // broadcast v (1x128 bf16) to LDS so every lane can build its A-fragment
  short* vl = smem + w*128;
  #pragma unroll
  for (int q = 0; q < 2; ++q){
    const int ct = lg*2 + q;
    vl[ct*16 + l15] = f2bf(v8[ct]);
  }

  // RACE FIX (round 2 bug): compiler may reorder the s16x8 LDS read above the
  // scalar short LDS writes (no provable alias). Full barrier forces order.
  __syncthreads();

  // ---- GEMM2: v (replicated into all 16 A-rows) @ W2 -> 1x128 ----
  f32x4 acc2[8];
  #pragma unroll
  for (int ct = 0; ct < 8; ++ct) acc2[ct] = (f32x4){0.f,0.f,0.f,0.f};

  s16x8 av[4];
  #pragma unroll
  for (int ks2 = 0; ks2 < 4; ++ks2)
    av[ks2] = *(const s16x8*)(vl + ks2*32 + lg*8);   // A[row][k]=v[k], any row

  #pragma unroll
  for (int ks2 = 0; ks2 < 4; ++ks2){
    const short* wb = W2f + ks2*4096 + lane*8;
    #pragma unroll
    for (int ct = 0; ct < 8; ++ct){
      s16x8 bf = *(const s16x8*)(wb + ct*512);
      acc2[ct] = __builtin_amdgcn_mfma_f32_16x16x32_bf16(av[ks2], bf, acc2[ct], 0,0,0);
    }
  }

  // ---- epilogue: + 32*b2, /30, + h_V, LayerNorm, store ----
  float res[8];
  float vs = 0.f, vq = 0.f;
  #pragma unroll
  for (int ct = 0; ct < 8; ++ct){
    const int c = ct*16 + l15;
    float dh  = (acc2[ct][0] + 32.0f * W2b[c]) * (1.0f/30.0f);
    float val = hV[nodeoff + c] + dh;
    res[ct] = val;
    vs += val; vq += val*val;
  }
  vs += __shfl_xor(vs, 1, 64);  vs += __shfl_xor(vs, 2, 64);
  vs += __shfl_xor(vs, 4, 64);  vs += __shfl_xor(vs, 8, 64);
  vq += __shfl_xor(vq, 1, 64);  vq += __shfl_xor(vq, 2, 64);
  vq += __shfl_xor(vq, 4, 64);  vq += __shfl_xor(vq, 8, 64);
  const float mu  = vs * (1.0f/128.0f);
  const float var = vq * (1.0f/128.0f) - mu*mu;
  const float rs  = rsqrtf(var + 1e-5f);

  #pragma unroll
  for (int q = 0; q < 2; ++q){
    const int ct = lg*2 + q;
    const int c  = ct*16 + l15;
    out[nodeoff + c] = (res[ct] - mu) * rs * lng[c] + lnb[c];
  }
}

extern "C" void kernel_launch(void* const* d_in, const int* in_sizes, int n_in,
                              void* d_out, int out_size, void* d_ws, size_t ws_size,
                              hipStream_t stream) {
  const float* hS  = (const float*)d_in[0];
  const float* hV  = (const float*)d_in[1];
  const float* hE  = (const float*)d_in[2];
  const int*   Ei  = (const int*)d_in[3];
  const float* mk  = (const float*)d_in[4];
  const float* W1w = (const float*)d_in[5];
  const float* W1b = (const float*)d_in[6];
  const float* W2w = (const float*)d_in[7];
  const float* W2b = (const float*)d_in[8];
  const float* lng = (const float*)d_in[9];
  const float* lnb = (const float*)d_in[10];

  short* W1f = (short*)d_ws;                       // 65536 bf16 = 128 KB
  short* W2f = W1f + 65536;                        // 16384 bf16 = 32 KB
  unsigned* flag = (unsigned*)((char*)d_ws + 163840);

  pack_w<<<320, 256, 0, stream>>>(W1w, W2w, W1f, W2f);
  detect_init<<<1, 64, 0, stream>>>(flag);
  detect_idx<<<512, 256, 0, stream>>>((const unsigned*)Ei, flag);
  fused<<<2048, 256, 0, stream>>>(hS, hV, hE, Ei, mk, W1b, W2b, lng, lnb,
                                  W1f, W2f, flag, (float*)d_out);
}

// Round 4
// 107.275 us; speedup vs baseline: 1.3283x; 1.0432x over previous
//
#include <hip/hip_runtime.h>
#include <math.h>

typedef float f32x4 __attribute__((ext_vector_type(4)));
typedef short s16x8 __attribute__((ext_vector_type(8)));
typedef unsigned u32x4 __attribute__((ext_vector_type(4)));

#define N_NODES 2048
#define KEDGE 32
#define HDIM 128

__device__ __forceinline__ short f2bf(float f){
  unsigned u = __builtin_bit_cast(unsigned, f);
  u += 0x7fffu + ((u >> 16) & 1u);
  return (short)(u >> 16);
}

__device__ __forceinline__ unsigned cvt_pk_bf16(float a, float b){
  unsigned r;
  asm("v_cvt_pk_bf16_f32 %0, %1, %2" : "=v"(r) : "v"(a), "v"(b));
  return r;
}

// tanh-form GELU via exp2+rcp: max abs error vs exact ~5e-4
__device__ __forceinline__ float fast_gelu(float x){
  float t = x * (-2.3022078f - 0.1029527f * x * x);
  float e = __builtin_amdgcn_exp2f(t);
  return x * __builtin_amdgcn_rcpf(1.0f + e);
}

__device__ __forceinline__ void gld16(const void* g, void* l){
  __builtin_amdgcn_global_load_lds(
      (const __attribute__((address_space(1))) void*)g,
      (__attribute__((address_space(3))) void*)l, 16, 0, 0);
}

// Pack W1 (512x128) and W2 (128x128) fp32 -> bf16 in MFMA B-fragment order:
// elem((ks,ct,lane,j)) = W[ks*32 + (lane>>4)*8 + j][ct*16 + (lane&15)]
__global__ void pack_w(const float* __restrict__ W1, const float* __restrict__ W2,
                       short* __restrict__ W1f, short* __restrict__ W2f){
  int t = blockIdx.x * 256 + threadIdx.x;
  if (t < 65536){
    int ks = t >> 12, r = t & 4095;
    int ct = r >> 9;  r &= 511;
    int lane = r >> 3, j = r & 7;
    int k = ks*32 + (lane>>4)*8 + j;
    int n = ct*16 + (lane&15);
    W1f[t] = f2bf(W1[k*128 + n]);
  } else if (t < 81920){
    int t2 = t - 65536;
    int ks = t2 >> 12, r = t2 & 4095;
    int ct = r >> 9;  r &= 511;
    int lane = r >> 3, j = r & 7;
    int k = ks*32 + (lane>>4)*8 + j;
    int n = ct*16 + (lane&15);
    W2f[t2] = f2bf(W2[k*128 + n]);
  }
}

// E_idx dtype detection: if stored as int64, every odd 32-bit word is 0.
__global__ void detect_init(unsigned* flag){
  if (blockIdx.x == 0 && threadIdx.x == 0) *flag = 0u;
}
__global__ void detect_idx(const unsigned* __restrict__ e, unsigned* flag){
  int t = blockIdx.x * 256 + threadIdx.x;          // t < 131072
  unsigned v = e[2*t + 1];
  unsigned long long m = __ballot(v != 0u);
  if ((threadIdx.x & 63) == 0 && m) atomicOr(flag, 1u);
}

__global__ __launch_bounds__(512, 4)
void fused(const float* __restrict__ hS, const float* __restrict__ hV,
           const float* __restrict__ hE, const int* __restrict__ Eidx,
           const float* __restrict__ mask,
           const float* __restrict__ W1b, const float* __restrict__ W2b,
           const float* __restrict__ lng, const float* __restrict__ lnb,
           const short* __restrict__ W1f, const short* __restrict__ W2f,
           const unsigned* __restrict__ idx_flag,
           float* __restrict__ out)
{
  // 64 KB: one half of W1 (k-steps p*8 .. p*8+7), staged once per phase.
  // + 2 KB v-broadcast area (8 waves x 128 bf16).
  __shared__ short smem[33792];

  const int tid  = threadIdx.x;
  const int w    = tid >> 6;          // 8 waves, one node each
  const int lane = tid & 63;
  const int l15  = lane & 15;
  const int lg   = lane >> 4;

  const int ng = blockIdx.x * 8 + w;     // global node id (= b*N + n)
  const int b  = ng >> 11;
  const long nodeoff = (long)ng * HDIM;
  const int  ebase   = ng * KEDGE;

  const int is64 = (*idx_flag == 0u);    // all odd words zero -> int64

  // per row-tile (rt=0,1) edge info: row = rt*16 + l15
  float mval[2];
  const float* segbase[4][2];
  #pragma unroll
  for (int rt = 0; rt < 2; ++rt){
    int e = ebase + rt*16 + l15;
    int eidx = is64 ? Eidx[2*e] : Eidx[e];
    mval[rt] = mask[e];
    segbase[0][rt] = hV + nodeoff;
    segbase[1][rt] = hE + (long)e * 128;
    segbase[2][rt] = hS + (long)(b*N_NODES + eidx) * 128;
    segbase[3][rt] = hV + (long)(b*N_NODES + eidx) * 128;
  }

  f32x4 acc1[2][8];
  #pragma unroll
  for (int rt = 0; rt < 2; ++rt)
    #pragma unroll
    for (int ct = 0; ct < 8; ++ct)
      acc1[rt][ct] = (f32x4){0.f,0.f,0.f,0.f};

  auto loadA = [&](int ks, s16x8* af){
    const int seg = ks >> 2;                 // compile-time (full unroll)
    const int off = (ks & 3)*32 + lg*8;
    #pragma unroll
    for (int rt = 0; rt < 2; ++rt){
      if (seg == 0 && rt == 1){ af[1] = af[0]; continue; }  // h_V bcast: rows equal
      const float* p = segbase[seg][rt] + off;
      float4 x = *(const float4*)p;
      float4 y = *(const float4*)(p + 4);
      float sc = (seg == 0) ? 1.0f : mval[rt];
      u32x4 pk;
      pk[0] = cvt_pk_bf16(x.x*sc, x.y*sc);
      pk[1] = cvt_pk_bf16(x.z*sc, x.w*sc);
      pk[2] = cvt_pk_bf16(y.x*sc, y.y*sc);
      pk[3] = cvt_pk_bf16(y.z*sc, y.w*sc);
      af[rt] = __builtin_bit_cast(s16x8, pk);
    }
  };

  // stage one 64 KB half of W1f (k-steps p*8..p*8+7): 8 chunks x 8 KB
  auto stageHalf = [&](int p){
    const short* g0 = W1f + p*32768 + w*512 + lane*8;
    short* l0 = smem + w*512;                // wave-uniform dest (+lane*16B by HW)
    #pragma unroll
    for (int q = 0; q < 8; ++q) gld16(g0 + q*4096, l0 + q*4096);
  };

  // ---- GEMM1: [32 x 512] @ W1 -> acc1 [32 x 128]; barrier-free inner loops ----
  #pragma unroll
  for (int p = 0; p < 2; ++p){
    s16x8 Acur[2], Anext[2];
    loadA(p*8, Acur);                        // issue gathers before stage drain
    stageHalf(p);
    __syncthreads();                         // half p visible
    #pragma unroll
    for (int k = 0; k < 8; ++k){
      if (k < 7) loadA(p*8 + k + 1, Anext);
      const short* bb = smem + k*4096 + lane*8;
      #pragma unroll
      for (int ct = 0; ct < 8; ++ct){
        s16x8 bf = *(const s16x8*)(bb + ct*512);
        acc1[0][ct] = __builtin_amdgcn_mfma_f32_16x16x32_bf16(Acur[0], bf, acc1[0][ct], 0,0,0);
        acc1[1][ct] = __builtin_amdgcn_mfma_f32_16x16x32_bf16(Acur[1], bf, acc1[1][ct], 0,0,0);
      }
      if (k < 7){ Acur[0] = Anext[0]; Acur[1] = Anext[1]; }
    }
    __syncthreads();                         // all waves done reading half p
  }

  // ---- bias + GELU, reduce over 32 edges in registers ----
  // (row-sum commutes with GEMM2: dh = (sum_e gelu(h_e)) @ W2 + 32*b2)
  float b1v[8];
  #pragma unroll
  for (int ct = 0; ct < 8; ++ct) b1v[ct] = W1b[ct*16 + l15];

  float v8[8];
  #pragma unroll
  for (int ct = 0; ct < 8; ++ct){
    float s = 0.f;
    #pragma unroll
    for (int rt = 0; rt < 2; ++rt)
      #pragma unroll
      for (int i = 0; i < 4; ++i)
        s += fast_gelu(acc1[rt][ct][i] + b1v[ct]);
    s += __shfl_xor(s, 16, 64);
    s += __shfl_xor(s, 32, 64);              // col = ct*16 + l15
    v8[ct] = s;
  }

  // broadcast v (1x128 bf16) via LDS (disjoint area at 32768)
  short* vl = smem + 32768 + w*128;
  #pragma unroll
  for (int q = 0; q < 2; ++q){
    const int ct = lg*2 + q;
    vl[ct*16 + l15] = f2bf(v8[ct]);
  }
  __syncthreads();   // order scalar writes vs vector reads (round-2 lesson)

  // ---- GEMM2: v (replicated rows) @ W2 -> 1x128; W2f read from L2 ----
  f32x4 acc2[8];
  #pragma unroll
  for (int ct = 0; ct < 8; ++ct) acc2[ct] = (f32x4){0.f,0.f,0.f,0.f};

  s16x8 av[4];
  #pragma unroll
  for (int ks2 = 0; ks2 < 4; ++ks2)
    av[ks2] = *(const s16x8*)(vl + ks2*32 + lg*8);

  #pragma unroll
  for (int ks2 = 0; ks2 < 4; ++ks2){
    const short* wb = W2f + ks2*4096 + lane*8;
    #pragma unroll
    for (int ct = 0; ct < 8; ++ct){
      s16x8 bf = *(const s16x8*)(wb + ct*512);
      acc2[ct] = __builtin_amdgcn_mfma_f32_16x16x32_bf16(av[ks2], bf, acc2[ct], 0,0,0);
    }
  }

  // ---- epilogue: + 32*b2, /30, + h_V, LayerNorm, store ----
  float res[8];
  float vs = 0.f, vq = 0.f;
  #pragma unroll
  for (int ct = 0; ct < 8; ++ct){
    const int c = ct*16 + l15;
    float dh  = (acc2[ct][0] + 32.0f * W2b[c]) * (1.0f/30.0f);
    float val = hV[nodeoff + c] + dh;
    res[ct] = val;
    vs += val; vq += val*val;
  }
  vs += __shfl_xor(vs, 1, 64);  vs += __shfl_xor(vs, 2, 64);
  vs += __shfl_xor(vs, 4, 64);  vs += __shfl_xor(vs, 8, 64);
  vq += __shfl_xor(vq, 1, 64);  vq += __shfl_xor(vq, 2, 64);
  vq += __shfl_xor(vq, 4, 64);  vq += __shfl_xor(vq, 8, 64);
  const float mu  = vs * (1.0f/128.0f);
  const float var = vq * (1.0f/128.0f) - mu*mu;
  const float rs  = rsqrtf(var + 1e-5f);

  #pragma unroll
  for (int q = 0; q < 2; ++q){
    const int ct = lg*2 + q;
    const int c  = ct*16 + l15;
    out[nodeoff + c] = (res[ct] - mu) * rs * lng[c] + lnb[c];
  }
}

extern "C" void kernel_launch(void* const* d_in, const int* in_sizes, int n_in,
                              void* d_out, int out_size, void* d_ws, size_t ws_size,
                              hipStream_t stream) {
  const float* hS  = (const float*)d_in[0];
  const float* hV  = (const float*)d_in[1];
  const float* hE  = (const float*)d_in[2];
  const int*   Ei  = (const int*)d_in[3];
  const float* mk  = (const float*)d_in[4];
  const float* W1w = (const float*)d_in[5];
  const float* W1b = (const float*)d_in[6];
  const float* W2w = (const float*)d_in[7];
  const float* W2b = (const float*)d_in[8];
  const float* lng = (const float*)d_in[9];
  const float* lnb = (const float*)d_in[10];

  short* W1f = (short*)d_ws;                       // 65536 bf16 = 128 KB
  short* W2f = W1f + 65536;                        // 16384 bf16 = 32 KB
  unsigned* flag = (unsigned*)((char*)d_ws + 163840);

  pack_w<<<320, 256, 0, stream>>>(W1w, W2w, W1f, W2f);
  detect_init<<<1, 64, 0, stream>>>(flag);
  detect_idx<<<512, 256, 0, stream>>>((const unsigned*)Ei, flag);
  fused<<<1024, 512, 0, stream>>>(hS, hV, hE, Ei, mk, W1b, W2b, lng, lnb,
                                  W1f, W2f, flag, (float*)d_out);
}

// Round 5
// 98.643 us; speedup vs baseline: 1.4445x; 1.0875x over previous
//
#include <hip/hip_runtime.h>
#include <math.h>

typedef float f32x4 __attribute__((ext_vector_type(4)));
typedef short s16x8 __attribute__((ext_vector_type(8)));
typedef unsigned u32x4 __attribute__((ext_vector_type(4)));

#define N_NODES 2048
#define KEDGE 32
#define HDIM 128

__device__ __forceinline__ short f2bf(float f){
  unsigned u = __builtin_bit_cast(unsigned, f);
  u += 0x7fffu + ((u >> 16) & 1u);
  return (short)(u >> 16);
}

__device__ __forceinline__ unsigned cvt_pk_bf16(float a, float b){
  unsigned r;
  asm("v_cvt_pk_bf16_f32 %0, %1, %2" : "=v"(r) : "v"(a), "v"(b));
  return r;
}

// tanh-form GELU via exp2+rcp: max abs error vs exact ~5e-4
__device__ __forceinline__ float fast_gelu(float x){
  float t = x * (-2.3022078f - 0.1029527f * x * x);
  float e = __builtin_amdgcn_exp2f(t);
  return x * __builtin_amdgcn_rcpf(1.0f + e);
}

__device__ __forceinline__ void gld16(const void* g, void* l){
  __builtin_amdgcn_global_load_lds(
      (const __attribute__((address_space(1))) void*)g,
      (__attribute__((address_space(3))) void*)l, 16, 0, 0);
}

__device__ __forceinline__ f32x4 mfma16(s16x8 a, s16x8 b, f32x4 c){
  return __builtin_amdgcn_mfma_f32_16x16x32_bf16(a, b, c, 0, 0, 0);
}

// Pack W1 (512x128) and W2 (128x128) fp32 -> bf16 in MFMA B-fragment order:
// elem((ks,ct,lane,j)) = W[ks*32 + (lane>>4)*8 + j][ct*16 + (lane&15)]
__global__ void pack_w(const float* __restrict__ W1, const float* __restrict__ W2,
                       short* __restrict__ W1f, short* __restrict__ W2f){
  int t = blockIdx.x * 256 + threadIdx.x;
  if (t < 65536){
    int ks = t >> 12, r = t & 4095;
    int ct = r >> 9;  r &= 511;
    int lane = r >> 3, j = r & 7;
    int k = ks*32 + (lane>>4)*8 + j;
    int n = ct*16 + (lane&15);
    W1f[t] = f2bf(W1[k*128 + n]);
  } else if (t < 81920){
    int t2 = t - 65536;
    int ks = t2 >> 12, r = t2 & 4095;
    int ct = r >> 9;  r &= 511;
    int lane = r >> 3, j = r & 7;
    int k = ks*32 + (lane>>4)*8 + j;
    int n = ct*16 + (lane&15);
    W2f[t2] = f2bf(W2[k*128 + n]);
  }
}

// E_idx dtype detection: if stored as int64, every odd 32-bit word is 0.
__global__ void detect_init(unsigned* flag){
  if (blockIdx.x == 0 && threadIdx.x == 0) *flag = 0u;
}
__global__ void detect_idx(const unsigned* __restrict__ e, unsigned* flag){
  int t = blockIdx.x * 256 + threadIdx.x;          // t < 131072
  unsigned v = e[2*t + 1];
  unsigned long long m = __ballot(v != 0u);
  if ((threadIdx.x & 63) == 0 && m) atomicOr(flag, 1u);
}

// Precompute per node m:
//   Z[m]  = hS(m)@W1c + hV(m)@W1d            (f32, 128)
//   U'[m] = hV(m)@W1a + b1                   (f32, 128)
// Wave = 16 nodes. 128 blocks x 4 waves = 8192 nodes.
__global__ __launch_bounds__(256)
void prep_zu(const float* __restrict__ hS, const float* __restrict__ hV,
             const float* __restrict__ b1, const short* __restrict__ W1f,
             float* __restrict__ Z, float* __restrict__ U){
  const int tid = threadIdx.x;
  const int w = tid >> 6, lane = tid & 63, l15 = lane & 15, lg = lane >> 4;
  const int nb = (blockIdx.x*4 + w)*16;

  f32x4 accz[8], accu[8];
  #pragma unroll
  for (int ct = 0; ct < 8; ++ct){ accz[ct] = (f32x4){0,0,0,0}; accu[ct] = (f32x4){0,0,0,0}; }

  // phase 1: Z += hS @ W1c (packed ks 8..11)
  #pragma unroll
  for (int ks = 0; ks < 4; ++ks){
    const float* p = hS + (long)(nb + l15)*128 + ks*32 + lg*8;
    float4 x = *(const float4*)p, y = *(const float4*)(p + 4);
    u32x4 pk;
    pk[0] = cvt_pk_bf16(x.x, x.y); pk[1] = cvt_pk_bf16(x.z, x.w);
    pk[2] = cvt_pk_bf16(y.x, y.y); pk[3] = cvt_pk_bf16(y.z, y.w);
    s16x8 a = __builtin_bit_cast(s16x8, pk);
    #pragma unroll
    for (int ct = 0; ct < 8; ++ct){
      s16x8 bf = *(const s16x8*)(W1f + (8+ks)*4096 + ct*512 + lane*8);
      accz[ct] = mfma16(a, bf, accz[ct]);
    }
  }
  // phase 2: Z += hV @ W1d (ks 12..15); U += hV @ W1a (ks 0..3)
  #pragma unroll
  for (int ks = 0; ks < 4; ++ks){
    const float* p = hV + (long)(nb + l15)*128 + ks*32 + lg*8;
    float4 x = *(const float4*)p, y = *(const float4*)(p + 4);
    u32x4 pk;
    pk[0] = cvt_pk_bf16(x.x, x.y); pk[1] = cvt_pk_bf16(x.z, x.w);
    pk[2] = cvt_pk_bf16(y.x, y.y); pk[3] = cvt_pk_bf16(y.z, y.w);
    s16x8 a = __builtin_bit_cast(s16x8, pk);
    #pragma unroll
    for (int ct = 0; ct < 8; ++ct){
      s16x8 bfd = *(const s16x8*)(W1f + (12+ks)*4096 + ct*512 + lane*8);
      accz[ct] = mfma16(a, bfd, accz[ct]);
      s16x8 bfa = *(const s16x8*)(W1f + (0+ks)*4096 + ct*512 + lane*8);
      accu[ct] = mfma16(a, bfa, accu[ct]);
    }
  }

  float b1v[8];
  #pragma unroll
  for (int ct = 0; ct < 8; ++ct) b1v[ct] = b1[ct*16 + l15];

  #pragma unroll
  for (int ct = 0; ct < 8; ++ct)
    #pragma unroll
    for (int i = 0; i < 4; ++i){
      const long row = nb + lg*4 + i;
      Z[row*128 + ct*16 + l15] = accz[ct][i];
      U[row*128 + ct*16 + l15] = accu[ct][i] + b1v[ct];
    }
}

// Fast fused kernel: per edge pre-act = U'(n) + mask*(hE@W1b) + mask*Z[idx].
// GEMM1 K=128 (hE, LDS B) + Z injected via identity-MFMA. Then gelu-sum,
// GEMM2, LayerNorm. 4 waves = 4 nodes per block.
__global__ __launch_bounds__(256, 3)
void fusedF(const float* __restrict__ hE, const int* __restrict__ Eidx,
            const float* __restrict__ mask, const float* __restrict__ hV,
            const float* __restrict__ W2b, const float* __restrict__ lng,
            const float* __restrict__ lnb, const short* __restrict__ W1f,
            const short* __restrict__ W2f, const float* __restrict__ Z,
            const float* __restrict__ U, const unsigned* __restrict__ idx_flag,
            float* __restrict__ out)
{
  __shared__ short smem[16896];   // 32 KB W1b + 1 KB v-broadcast

  const int tid  = threadIdx.x;
  const int w    = tid >> 6;
  const int lane = tid & 63;
  const int l15  = lane & 15;
  const int lg   = lane >> 4;

  const int bid  = (int)blockIdx.x;
  const int bswz = (bid & 7)*256 + (bid >> 3);   // XCD swizzle (2048 % 8 == 0)
  const int ng   = bswz*4 + w;
  const int b    = ng >> 11;
  const long nodeoff = (long)ng * HDIM;
  const int  ebase   = ng * KEDGE;

  // earliest possible: full-depth hE prefetch (16 float4 in flight)
  float4 eraw[4][2][2];
  #pragma unroll
  for (int ks = 0; ks < 4; ++ks)
    #pragma unroll
    for (int rt = 0; rt < 2; ++rt){
      const float* p = hE + (long)(ebase + rt*16 + l15)*128 + ks*32 + lg*8;
      eraw[ks][rt][0] = *(const float4*)p;
      eraw[ks][rt][1] = *(const float4*)(p + 4);
    }

  const int is64 = (*idx_flag == 0u);
  int eidx[2]; float mval[2];
  #pragma unroll
  for (int rt = 0; rt < 2; ++rt){
    int e = ebase + rt*16 + l15;
    eidx[rt] = is64 ? Eidx[2*e] : Eidx[e];
    mval[rt] = mask[e];
  }

  // stage W1b (packed ks 4..7, 32 KB) via global_load_lds
  {
    const short* g0 = W1f + 16384 + w*512 + lane*8;
    short* l0 = smem + w*512;
    #pragma unroll
    for (int q = 0; q < 8; ++q) gld16(g0 + q*2048, l0 + q*2048);
  }
  __syncthreads();

  float uv[8];
  #pragma unroll
  for (int ct = 0; ct < 8; ++ct) uv[ct] = U[nodeoff + ct*16 + l15];

  f32x4 acc1[2][8];
  #pragma unroll
  for (int rt = 0; rt < 2; ++rt)
    #pragma unroll
    for (int ct = 0; ct < 8; ++ct) acc1[rt][ct] = (f32x4){0,0,0,0};

  // ---- hE @ W1b, with z-row gathers issued per-ks (stay in flight) ----
  float4 zraw[4][2][2];
  #pragma unroll
  for (int ks = 0; ks < 4; ++ks){
    #pragma unroll
    for (int rt = 0; rt < 2; ++rt){
      const float* zp = Z + (long)(b*N_NODES + eidx[rt])*128 + ks*32 + lg*8;
      zraw[ks][rt][0] = *(const float4*)zp;
      zraw[ks][rt][1] = *(const float4*)(zp + 4);
    }
    s16x8 a[2];
    #pragma unroll
    for (int rt = 0; rt < 2; ++rt){
      float4 x = eraw[ks][rt][0], y = eraw[ks][rt][1];
      float sc = mval[rt];
      u32x4 pk;
      pk[0] = cvt_pk_bf16(x.x*sc, x.y*sc); pk[1] = cvt_pk_bf16(x.z*sc, x.w*sc);
      pk[2] = cvt_pk_bf16(y.x*sc, y.y*sc); pk[3] = cvt_pk_bf16(y.z*sc, y.w*sc);
      a[rt] = __builtin_bit_cast(s16x8, pk);
    }
    const short* bb = smem + ks*4096 + lane*8;
    #pragma unroll
    for (int ct = 0; ct < 8; ++ct){
      s16x8 bf = *(const s16x8*)(bb + ct*512);
      acc1[0][ct] = mfma16(a[0], bf, acc1[0][ct]);
      acc1[1][ct] = mfma16(a[1], bf, acc1[1][ct]);
    }
  }

  // ---- inject Z[idx] via identity-MFMA ----
  // B-frag of I for ct = 2*zks + c2: lane nonzero iff (lg>>1)==c2, at
  // elem j = l15 - 8*(lg&1)  (in [0,8)); independent of zks.
  s16x8 ifr[2];
  #pragma unroll
  for (int c2 = 0; c2 < 2; ++c2){
    const int active = ((lg >> 1) == c2);
    const int j = l15 - 8*(lg & 1);
    s16x8 f;
    #pragma unroll
    for (int e = 0; e < 8; ++e)
      f[e] = (active && j == e) ? (short)0x3F80 : (short)0;
    ifr[c2] = f;
  }
  #pragma unroll
  for (int zks = 0; zks < 4; ++zks){
    s16x8 a[2];
    #pragma unroll
    for (int rt = 0; rt < 2; ++rt){
      float4 x = zraw[zks][rt][0], y = zraw[zks][rt][1];
      float sc = mval[rt];
      u32x4 pk;
      pk[0] = cvt_pk_bf16(x.x*sc, x.y*sc); pk[1] = cvt_pk_bf16(x.z*sc, x.w*sc);
      pk[2] = cvt_pk_bf16(y.x*sc, y.y*sc); pk[3] = cvt_pk_bf16(y.z*sc, y.w*sc);
      a[rt] = __builtin_bit_cast(s16x8, pk);
    }
    #pragma unroll
    for (int c2 = 0; c2 < 2; ++c2){
      const int ct = zks*2 + c2;
      acc1[0][ct] = mfma16(a[0], ifr[c2], acc1[0][ct]);
      acc1[1][ct] = mfma16(a[1], ifr[c2], acc1[1][ct]);
    }
  }

  // ---- U' + GELU, reduce over 32 edges in registers ----
  float v8[8];
  #pragma unroll
  for (int ct = 0; ct < 8; ++ct){
    float s = 0.f;
    #pragma unroll
    for (int rt = 0; rt < 2; ++rt)
      #pragma unroll
      for (int i = 0; i < 4; ++i)
        s += fast_gelu(acc1[rt][ct][i] + uv[ct]);
    s += __shfl_xor(s, 16, 64);
    s += __shfl_xor(s, 32, 64);
    v8[ct] = s;
  }

  // broadcast v (1x128 bf16) via LDS
  short* vl = smem + 16384 + w*128;
  #pragma unroll
  for (int q = 0; q < 2; ++q){
    const int ct = lg*2 + q;
    vl[ct*16 + l15] = f2bf(v8[ct]);
  }
  __syncthreads();   // order scalar writes vs vector reads (round-2 lesson)

  // ---- GEMM2: v @ W2 (W2f from L2) ----
  f32x4 acc2[8];
  #pragma unroll
  for (int ct = 0; ct < 8; ++ct) acc2[ct] = (f32x4){0,0,0,0};

  s16x8 av[4];
  #pragma unroll
  for (int ks2 = 0; ks2 < 4; ++ks2)
    av[ks2] = *(const s16x8*)(vl + ks2*32 + lg*8);

  #pragma unroll
  for (int ks2 = 0; ks2 < 4; ++ks2){
    const short* wb = W2f + ks2*4096 + lane*8;
    #pragma unroll
    for (int ct = 0; ct < 8; ++ct){
      s16x8 bf = *(const s16x8*)(wb + ct*512);
      acc2[ct] = mfma16(av[ks2], bf, acc2[ct]);
    }
  }

  // ---- epilogue: + 32*b2, /30, + h_V, LayerNorm, store ----
  float res[8];
  float vs = 0.f, vq = 0.f;
  #pragma unroll
  for (int ct = 0; ct < 8; ++ct){
    const int c = ct*16 + l15;
    float dh  = (acc2[ct][0] + 32.0f * W2b[c]) * (1.0f/30.0f);
    float val = hV[nodeoff + c] + dh;
    res[ct] = val;
    vs += val; vq += val*val;
  }
  vs += __shfl_xor(vs, 1, 64);  vs += __shfl_xor(vs, 2, 64);
  vs += __shfl_xor(vs, 4, 64);  vs += __shfl_xor(vs, 8, 64);
  vq += __shfl_xor(vq, 1, 64);  vq += __shfl_xor(vq, 2, 64);
  vq += __shfl_xor(vq, 4, 64);  vq += __shfl_xor(vq, 8, 64);
  const float mu  = vs * (1.0f/128.0f);
  const float var = vq * (1.0f/128.0f) - mu*mu;
  const float rs  = rsqrtf(var + 1e-5f);

  #pragma unroll
  for (int q = 0; q < 2; ++q){
    const int ct = lg*2 + q;
    const int c  = ct*16 + l15;
    out[nodeoff + c] = (res[ct] - mu) * rs * lng[c] + lnb[c];
  }
}

// ---- fallback: round-4 kernel (used when ws too small for Z/U tables) ----
__global__ __launch_bounds__(512, 4)
void fusedR4(const float* __restrict__ hS, const float* __restrict__ hV,
             const float* __restrict__ hE, const int* __restrict__ Eidx,
             const float* __restrict__ mask,
             const float* __restrict__ W1b, const float* __restrict__ W2b,
             const float* __restrict__ lng, const float* __restrict__ lnb,
             const short* __restrict__ W1f, const short* __restrict__ W2f,
             const unsigned* __restrict__ idx_flag,
             float* __restrict__ out)
{
  __shared__ short smem[33792];

  const int tid  = threadIdx.x;
  const int w    = tid >> 6;
  const int lane = tid & 63;
  const int l15  = lane & 15;
  const int lg   = lane >> 4;

  const int ng = blockIdx.x * 8 + w;
  const int b  = ng >> 11;
  const long nodeoff = (long)ng * HDIM;
  const int  ebase   = ng * KEDGE;

  const int is64 = (*idx_flag == 0u);

  float mval[2];
  const float* segbase[4][2];
  #pragma unroll
  for (int rt = 0; rt < 2; ++rt){
    int e = ebase + rt*16 + l15;
    int eidx = is64 ? Eidx[2*e] : Eidx[e];
    mval[rt] = mask[e];
    segbase[0][rt] = hV + nodeoff;
    segbase[1][rt] = hE + (long)e * 128;
    segbase[2][rt] = hS + (long)(b*N_NODES + eidx) * 128;
    segbase[3][rt] = hV + (long)(b*N_NODES + eidx) * 128;
  }

  f32x4 acc1[2][8];
  #pragma unroll
  for (int rt = 0; rt < 2; ++rt)
    #pragma unroll
    for (int ct = 0; ct < 8; ++ct)
      acc1[rt][ct] = (f32x4){0.f,0.f,0.f,0.f};

  auto loadA = [&](int ks, s16x8* af){
    const int seg = ks >> 2;
    const int off = (ks & 3)*32 + lg*8;
    #pragma unroll
    for (int rt = 0; rt < 2; ++rt){
      if (seg == 0 && rt == 1){ af[1] = af[0]; continue; }
      const float* p = segbase[seg][rt] + off;
      float4 x = *(const float4*)p;
      float4 y = *(const float4*)(p + 4);
      float sc = (seg == 0) ? 1.0f : mval[rt];
      u32x4 pk;
      pk[0] = cvt_pk_bf16(x.x*sc, x.y*sc);
      pk[1] = cvt_pk_bf16(x.z*sc, x.w*sc);
      pk[2] = cvt_pk_bf16(y.x*sc, y.y*sc);
      pk[3] = cvt_pk_bf16(y.z*sc, y.w*sc);
      af[rt] = __builtin_bit_cast(s16x8, pk);
    }
  };
  auto stageHalf = [&](int p){
    const short* g0 = W1f + p*32768 + w*512 + lane*8;
    short* l0 = smem + w*512;
    #pragma unroll
    for (int q = 0; q < 8; ++q) gld16(g0 + q*4096, l0 + q*4096);
  };

  #pragma unroll
  for (int p = 0; p < 2; ++p){
    s16x8 Acur[2], Anext[2];
    loadA(p*8, Acur);
    stageHalf(p);
    __syncthreads();
    #pragma unroll
    for (int k = 0; k < 8; ++k){
      if (k < 7) loadA(p*8 + k + 1, Anext);
      const short* bb = smem + k*4096 + lane*8;
      #pragma unroll
      for (int ct = 0; ct < 8; ++ct){
        s16x8 bf = *(const s16x8*)(bb + ct*512);
        acc1[0][ct] = mfma16(Acur[0], bf, acc1[0][ct]);
        acc1[1][ct] = mfma16(Acur[1], bf, acc1[1][ct]);
      }
      if (k < 7){ Acur[0] = Anext[0]; Acur[1] = Anext[1]; }
    }
    __syncthreads();
  }

  float b1v[8];
  #pragma unroll
  for (int ct = 0; ct < 8; ++ct) b1v[ct] = W1b[ct*16 + l15];

  float v8[8];
  #pragma unroll
  for (int ct = 0; ct < 8; ++ct){
    float s = 0.f;
    #pragma unroll
    for (int rt = 0; rt < 2; ++rt)
      #pragma unroll
      for (int i = 0; i < 4; ++i)
        s += fast_gelu(acc1[rt][ct][i] + b1v[ct]);
    s += __shfl_xor(s, 16, 64);
    s += __shfl_xor(s, 32, 64);
    v8[ct] = s;
  }

  short* vl = smem + 32768 + w*128;
  #pragma unroll
  for (int q = 0; q < 2; ++q){
    const int ct = lg*2 + q;
    vl[ct*16 + l15] = f2bf(v8[ct]);
  }
  __syncthreads();

  f32x4 acc2[8];
  #pragma unroll
  for (int ct = 0; ct < 8; ++ct) acc2[ct] = (f32x4){0.f,0.f,0.f,0.f};

  s16x8 av[4];
  #pragma unroll
  for (int ks2 = 0; ks2 < 4; ++ks2)
    av[ks2] = *(const s16x8*)(vl + ks2*32 + lg*8);

  #pragma unroll
  for (int ks2 = 0; ks2 < 4; ++ks2){
    const short* wb = W2f + ks2*4096 + lane*8;
    #pragma unroll
    for (int ct = 0; ct < 8; ++ct){
      s16x8 bf = *(const s16x8*)(wb + ct*512);
      acc2[ct] = mfma16(av[ks2], bf, acc2[ct]);
    }
  }

  float res[8];
  float vs = 0.f, vq = 0.f;
  #pragma unroll
  for (int ct = 0; ct < 8; ++ct){
    const int c = ct*16 + l15;
    float dh  = (acc2[ct][0] + 32.0f * W2b[c]) * (1.0f/30.0f);
    float val = hV[nodeoff + c] + dh;
    res[ct] = val;
    vs += val; vq += val*val;
  }
  vs += __shfl_xor(vs, 1, 64);  vs += __shfl_xor(vs, 2, 64);
  vs += __shfl_xor(vs, 4, 64);  vs += __shfl_xor(vs, 8, 64);
  vq += __shfl_xor(vq, 1, 64);  vq += __shfl_xor(vq, 2, 64);
  vq += __shfl_xor(vq, 4, 64);  vq += __shfl_xor(vq, 8, 64);
  const float mu  = vs * (1.0f/128.0f);
  const float var = vq * (1.0f/128.0f) - mu*mu;
  const float rs  = rsqrtf(var + 1e-5f);

  #pragma unroll
  for (int q = 0; q < 2; ++q){
    const int ct = lg*2 + q;
    const int c  = ct*16 + l15;
    out[nodeoff + c] = (res[ct] - mu) * rs * lng[c] + lnb[c];
  }
}

extern "C" void kernel_launch(void* const* d_in, const int* in_sizes, int n_in,
                              void* d_out, int out_size, void* d_ws, size_t ws_size,
                              hipStream_t stream) {
  const float* hS  = (const float*)d_in[0];
  const float* hV  = (const float*)d_in[1];
  const float* hE  = (const float*)d_in[2];
  const int*   Ei  = (const int*)d_in[3];
  const float* mk  = (const float*)d_in[4];
  const float* W1w = (const float*)d_in[5];
  const float* W1b = (const float*)d_in[6];
  const float* W2w = (const float*)d_in[7];
  const float* W2b = (const float*)d_in[8];
  const float* lng = (const float*)d_in[9];
  const float* lnb = (const float*)d_in[10];

  short* W1f = (short*)d_ws;                         // 131072 B
  short* W2f = W1f + 65536;                          // 32768 B
  unsigned* flag = (unsigned*)((char*)d_ws + 163840);
  float* Z = (float*)((char*)d_ws + 164096);         // 4 MB
  float* U = Z + 1048576;                            // 4 MB
  const size_t NEED = 164096ull + 2ull*4194304ull;

  pack_w<<<320, 256, 0, stream>>>(W1w, W2w, W1f, W2f);
  detect_init<<<1, 64, 0, stream>>>(flag);
  detect_idx<<<512, 256, 0, stream>>>((const unsigned*)Ei, flag);

  if (ws_size >= NEED){
    prep_zu<<<128, 256, 0, stream>>>(hS, hV, W1b, W1f, Z, U);
    fusedF<<<2048, 256, 0, stream>>>(hE, Ei, mk, hV, W2b, lng, lnb,
                                     W1f, W2f, Z, U, flag, (float*)d_out);
  } else {
    fusedR4<<<1024, 512, 0, stream>>>(hS, hV, hE, Ei, mk, W1b, W2b, lng, lnb,
                                      W1f, W2f, flag, (float*)d_out);
  }
}

// Round 6
// 92.973 us; speedup vs baseline: 1.5326x; 1.0610x over previous
//
#include <hip/hip_runtime.h>
#include <math.h>

typedef float f32x4 __attribute__((ext_vector_type(4)));
typedef short s16x8 __attribute__((ext_vector_type(8)));
typedef unsigned u32x4 __attribute__((ext_vector_type(4)));

#define N_NODES 2048
#define KEDGE 32
#define HDIM 128

__device__ __forceinline__ short f2bf(float f){
  unsigned u = __builtin_bit_cast(unsigned, f);
  u += 0x7fffu + ((u >> 16) & 1u);
  return (short)(u >> 16);
}

__device__ __forceinline__ unsigned cvt_pk_bf16(float a, float b){
  unsigned r;
  asm("v_cvt_pk_bf16_f32 %0, %1, %2" : "=v"(r) : "v"(a), "v"(b));
  return r;
}

// tanh-form GELU via exp2+rcp: max abs error vs exact ~5e-4
__device__ __forceinline__ float fast_gelu(float x){
  float t = x * (-2.3022078f - 0.1029527f * x * x);
  float e = __builtin_amdgcn_exp2f(t);
  return x * __builtin_amdgcn_rcpf(1.0f + e);
}

__device__ __forceinline__ f32x4 mfma16(s16x8 a, s16x8 b, f32x4 c){
  return __builtin_amdgcn_mfma_f32_16x16x32_bf16(a, b, c, 0, 0, 0);
}

// ---- prep kernel 1: pack W1/W2 to bf16 B-fragment order; init idx flag ----
// elem((ks,ct,lane,j)) = W[ks*32 + (lane>>4)*8 + j][ct*16 + (lane&15)]
__global__ void prep1(const float* __restrict__ W1, const float* __restrict__ W2,
                      short* __restrict__ W1f, short* __restrict__ W2f,
                      unsigned* __restrict__ flag){
  if (blockIdx.x == 320){
    if (threadIdx.x == 0) *flag = 0u;
    return;
  }
  int t = blockIdx.x * 256 + threadIdx.x;
  if (t < 65536){
    int ks = t >> 12, r = t & 4095;
    int ct = r >> 9;  r &= 511;
    int lane = r >> 3, j = r & 7;
    int k = ks*32 + (lane>>4)*8 + j;
    int n = ct*16 + (lane&15);
    W1f[t] = f2bf(W1[k*128 + n]);
  } else if (t < 81920){
    int t2 = t - 65536;
    int ks = t2 >> 12, r = t2 & 4095;
    int ct = r >> 9;  r &= 511;
    int lane = r >> 3, j = r & 7;
    int k = ks*32 + (lane>>4)*8 + j;
    int n = ct*16 + (lane&15);
    W2f[t2] = f2bf(W2[k*128 + n]);
  }
}

// ---- prep kernel 2: Z/U tables (blocks 0..127) + E_idx dtype detect (128..639)
//   Z[m]  = hS(m)@W1c + hV(m)@W1d   (f32, 128)
//   U'[m] = hV(m)@W1a + b1          (f32, 128)
__global__ __launch_bounds__(256)
void prep2(const float* __restrict__ hS, const float* __restrict__ hV,
           const float* __restrict__ b1, const short* __restrict__ W1f,
           float* __restrict__ Z, float* __restrict__ U,
           const unsigned* __restrict__ Ei_u, unsigned* __restrict__ flag){
  if (blockIdx.x >= 128){
    // detect: if Eidx is int64, every odd 32-bit word is 0
    int t = ((int)blockIdx.x - 128)*256 + threadIdx.x;   // t < 131072
    unsigned v = Ei_u[2*t + 1];
    unsigned long long m = __ballot(v != 0u);
    if ((threadIdx.x & 63) == 0 && m) atomicOr(flag, 1u);
    return;
  }
  const int tid = threadIdx.x;
  const int w = tid >> 6, lane = tid & 63, l15 = lane & 15, lg = lane >> 4;
  const int nb = ((int)blockIdx.x*4 + w)*16;

  f32x4 accz[8], accu[8];
  #pragma unroll
  for (int ct = 0; ct < 8; ++ct){ accz[ct] = (f32x4){0,0,0,0}; accu[ct] = (f32x4){0,0,0,0}; }

  // phase 1: Z += hS @ W1c (packed ks 8..11)
  #pragma unroll
  for (int ks = 0; ks < 4; ++ks){
    const float* p = hS + (long)(nb + l15)*128 + ks*32 + lg*8;
    float4 x = *(const float4*)p, y = *(const float4*)(p + 4);
    u32x4 pk;
    pk[0] = cvt_pk_bf16(x.x, x.y); pk[1] = cvt_pk_bf16(x.z, x.w);
    pk[2] = cvt_pk_bf16(y.x, y.y); pk[3] = cvt_pk_bf16(y.z, y.w);
    s16x8 a = __builtin_bit_cast(s16x8, pk);
    #pragma unroll
    for (int ct = 0; ct < 8; ++ct){
      s16x8 bf = *(const s16x8*)(W1f + (8+ks)*4096 + ct*512 + lane*8);
      accz[ct] = mfma16(a, bf, accz[ct]);
    }
  }
  // phase 2: Z += hV @ W1d (ks 12..15); U += hV @ W1a (ks 0..3)
  #pragma unroll
  for (int ks = 0; ks < 4; ++ks){
    const float* p = hV + (long)(nb + l15)*128 + ks*32 + lg*8;
    float4 x = *(const float4*)p, y = *(const float4*)(p + 4);
    u32x4 pk;
    pk[0] = cvt_pk_bf16(x.x, x.y); pk[1] = cvt_pk_bf16(x.z, x.w);
    pk[2] = cvt_pk_bf16(y.x, y.y); pk[3] = cvt_pk_bf16(y.z, y.w);
    s16x8 a = __builtin_bit_cast(s16x8, pk);
    #pragma unroll
    for (int ct = 0; ct < 8; ++ct){
      s16x8 bfd = *(const s16x8*)(W1f + (12+ks)*4096 + ct*512 + lane*8);
      accz[ct] = mfma16(a, bfd, accz[ct]);
      s16x8 bfa = *(const s16x8*)(W1f + (0+ks)*4096 + ct*512 + lane*8);
      accu[ct] = mfma16(a, bfa, accu[ct]);
    }
  }

  float b1v[8];
  #pragma unroll
  for (int ct = 0; ct < 8; ++ct) b1v[ct] = b1[ct*16 + l15];

  #pragma unroll
  for (int ct = 0; ct < 8; ++ct)
    #pragma unroll
    for (int i = 0; i < 4; ++i){
      const long row = nb + lg*4 + i;
      Z[row*128 + ct*16 + l15] = accz[ct][i];
      U[row*128 + ct*16 + l15] = accu[ct][i] + b1v[ct];
    }
}

// ---- fused kernel: per edge pre-act = U'(n) + mask*(hE@W1b) + mask*Z[idx].
// Barrier-free: B-fragments read direct from global (L1/L2-hot W1f/W2f),
// LDS only for the per-wave 256B v-broadcast. 4 waves = 4 nodes per block.
__global__ __launch_bounds__(256, 4)
void fusedF(const float* __restrict__ hE, const int* __restrict__ Eidx,
            const float* __restrict__ mask, const float* __restrict__ hV,
            const float* __restrict__ W2b, const float* __restrict__ lng,
            const float* __restrict__ lnb, const short* __restrict__ W1f,
            const short* __restrict__ W2f, const float* __restrict__ Z,
            const float* __restrict__ U, const unsigned* __restrict__ idx_flag,
            float* __restrict__ out)
{
  __shared__ short vbc[4][128];   // per-wave v broadcast (1 KB)

  const int tid  = threadIdx.x;
  const int w    = tid >> 6;
  const int lane = tid & 63;
  const int l15  = lane & 15;
  const int lg   = lane >> 4;

  const int bid  = (int)blockIdx.x;
  const int bswz = (bid & 7)*256 + (bid >> 3);   // XCD swizzle (2048 % 8 == 0)
  const int ng   = bswz*4 + w;
  const int b    = ng >> 11;
  const long nodeoff = (long)ng * HDIM;
  const int  ebase   = ng * KEDGE;

  const int is64 = (*idx_flag == 0u);
  int eidx[2]; float mval[2];
  #pragma unroll
  for (int rt = 0; rt < 2; ++rt){
    int e = ebase + rt*16 + l15;
    eidx[rt] = is64 ? Eidx[2*e] : Eidx[e];
    mval[rt] = mask[e];
  }

  // U' row for this node (issue early; consumed at gelu)
  float uv[8];
  #pragma unroll
  for (int ct = 0; ct < 8; ++ct) uv[ct] = U[nodeoff + ct*16 + l15];

  // identity B-fragments for the Z injection (exact in bf16):
  // for ct = 2*zks + c2: lane nonzero iff (lg>>1)==c2, at elem j = l15-8*(lg&1)
  s16x8 ifr[2];
  #pragma unroll
  for (int c2 = 0; c2 < 2; ++c2){
    const int active = ((lg >> 1) == c2);
    const int j = l15 - 8*(lg & 1);
    s16x8 f;
    #pragma unroll
    for (int e = 0; e < 8; ++e)
      f[e] = (active && j == e) ? (short)0x3F80 : (short)0;
    ifr[c2] = f;
  }

  f32x4 acc1[2][8];
  #pragma unroll
  for (int rt = 0; rt < 2; ++rt)
    #pragma unroll
    for (int ct = 0; ct < 8; ++ct) acc1[rt][ct] = (f32x4){0,0,0,0};

  const short* Wb = W1f + 16384;     // packed ks 4..7 region = W1b

  // rolling hE prefetch (depth 1 ks ahead = 4 float4 in flight)
  float4 ecur[2][2], enxt[2][2];
  #pragma unroll
  for (int rt = 0; rt < 2; ++rt){
    const float* p = hE + (long)(ebase + rt*16 + l15)*128 + lg*8;
    ecur[rt][0] = *(const float4*)p;
    ecur[rt][1] = *(const float4*)(p + 4);
  }

  #pragma unroll
  for (int ks = 0; ks < 4; ++ks){
    // issue next hE tile
    if (ks < 3){
      #pragma unroll
      for (int rt = 0; rt < 2; ++rt){
        const float* p = hE + (long)(ebase + rt*16 + l15)*128 + (ks+1)*32 + lg*8;
        enxt[rt][0] = *(const float4*)p;
        enxt[rt][1] = *(const float4*)(p + 4);
      }
    }
    // issue this ks's Z gathers (consumed after the 16 MFMAs below)
    float4 zr[2][2];
    #pragma unroll
    for (int rt = 0; rt < 2; ++rt){
      const float* zp = Z + (long)(b*N_NODES + eidx[rt])*128 + ks*32 + lg*8;
      zr[rt][0] = *(const float4*)zp;
      zr[rt][1] = *(const float4*)(zp + 4);
    }
    // hE A-fragments
    s16x8 a[2];
    #pragma unroll
    for (int rt = 0; rt < 2; ++rt){
      float4 x = ecur[rt][0], y = ecur[rt][1];
      float sc = mval[rt];
      u32x4 pk;
      pk[0] = cvt_pk_bf16(x.x*sc, x.y*sc); pk[1] = cvt_pk_bf16(x.z*sc, x.w*sc);
      pk[2] = cvt_pk_bf16(y.x*sc, y.y*sc); pk[3] = cvt_pk_bf16(y.z*sc, y.w*sc);
      a[rt] = __builtin_bit_cast(s16x8, pk);
    }
    // B-fragments direct from global (coalesced 1 KB/instr, L1/L2-hot)
    const short* bb = Wb + ks*4096 + lane*8;
    #pragma unroll
    for (int ct = 0; ct < 8; ++ct){
      s16x8 bf = *(const s16x8*)(bb + ct*512);
      acc1[0][ct] = mfma16(a[0], bf, acc1[0][ct]);
      acc1[1][ct] = mfma16(a[1], bf, acc1[1][ct]);
    }
    // Z injection via identity-MFMA (cols ct = 2ks, 2ks+1)
    s16x8 az[2];
    #pragma unroll
    for (int rt = 0; rt < 2; ++rt){
      float4 x = zr[rt][0], y = zr[rt][1];
      float sc = mval[rt];
      u32x4 pk;
      pk[0] = cvt_pk_bf16(x.x*sc, x.y*sc); pk[1] = cvt_pk_bf16(x.z*sc, x.w*sc);
      pk[2] = cvt_pk_bf16(y.x*sc, y.y*sc); pk[3] = cvt_pk_bf16(y.z*sc, y.w*sc);
      az[rt] = __builtin_bit_cast(s16x8, pk);
    }
    #pragma unroll
    for (int c2 = 0; c2 < 2; ++c2){
      const int ct = ks*2 + c2;
      acc1[0][ct] = mfma16(az[0], ifr[c2], acc1[0][ct]);
      acc1[1][ct] = mfma16(az[1], ifr[c2], acc1[1][ct]);
    }
    if (ks < 3){
      #pragma unroll
      for (int rt = 0; rt < 2; ++rt){
        ecur[rt][0] = enxt[rt][0]; ecur[rt][1] = enxt[rt][1];
      }
    }
  }

  // ---- U' + GELU, reduce over 32 edges in registers ----
  float v8[8];
  #pragma unroll
  for (int ct = 0; ct < 8; ++ct){
    float s = 0.f;
    #pragma unroll
    for (int rt = 0; rt < 2; ++rt)
      #pragma unroll
      for (int i = 0; i < 4; ++i)
        s += fast_gelu(acc1[rt][ct][i] + uv[ct]);
    s += __shfl_xor(s, 16, 64);
    s += __shfl_xor(s, 32, 64);              // col = ct*16 + l15
    v8[ct] = s;
  }

  // per-wave v broadcast via private LDS; wave-local fence instead of barrier
  short* vl = &vbc[w][0];
  #pragma unroll
  for (int q = 0; q < 2; ++q){
    const int ct = lg*2 + q;
    vl[ct*16 + l15] = f2bf(v8[ct]);
  }
  asm volatile("s_waitcnt lgkmcnt(0)" ::: "memory");  // order ds_write vs ds_read (r2 lesson)
  __builtin_amdgcn_sched_barrier(0);

  // ---- GEMM2: v (replicated rows) @ W2, W2f direct from global ----
  f32x4 acc2[8];
  #pragma unroll
  for (int ct = 0; ct < 8; ++ct) acc2[ct] = (f32x4){0,0,0,0};

  s16x8 av[4];
  #pragma unroll
  for (int ks2 = 0; ks2 < 4; ++ks2)
    av[ks2] = *(const s16x8*)(vl + ks2*32 + lg*8);

  #pragma unroll
  for (int ks2 = 0; ks2 < 4; ++ks2){
    const short* wb = W2f + ks2*4096 + lane*8;
    #pragma unroll
    for (int ct = 0; ct < 8; ++ct){
      s16x8 bf = *(const s16x8*)(wb + ct*512);
      acc2[ct] = mfma16(av[ks2], bf, acc2[ct]);
    }
  }

  // ---- epilogue: + 32*b2, /30, + h_V, LayerNorm, store ----
  float res[8];
  float vs = 0.f, vq = 0.f;
  #pragma unroll
  for (int ct = 0; ct < 8; ++ct){
    const int c = ct*16 + l15;
    float dh  = (acc2[ct][0] + 32.0f * W2b[c]) * (1.0f/30.0f);
    float val = hV[nodeoff + c] + dh;
    res[ct] = val;
    vs += val; vq += val*val;
  }
  vs += __shfl_xor(vs, 1, 64);  vs += __shfl_xor(vs, 2, 64);
  vs += __shfl_xor(vs, 4, 64);  vs += __shfl_xor(vs, 8, 64);
  vq += __shfl_xor(vq, 1, 64);  vq += __shfl_xor(vq, 2, 64);
  vq += __shfl_xor(vq, 4, 64);  vq += __shfl_xor(vq, 8, 64);
  const float mu  = vs * (1.0f/128.0f);
  const float var = vq * (1.0f/128.0f) - mu*mu;
  const float rs  = rsqrtf(var + 1e-5f);

  #pragma unroll
  for (int q = 0; q < 2; ++q){
    const int ct = lg*2 + q;
    const int c  = ct*16 + l15;
    out[nodeoff + c] = (res[ct] - mu) * rs * lng[c] + lnb[c];
  }
}

extern "C" void kernel_launch(void* const* d_in, const int* in_sizes, int n_in,
                              void* d_out, int out_size, void* d_ws, size_t ws_size,
                              hipStream_t stream) {
  const float* hS  = (const float*)d_in[0];
  const float* hV  = (const float*)d_in[1];
  const float* hE  = (const float*)d_in[2];
  const int*   Ei  = (const int*)d_in[3];
  const float* mk  = (const float*)d_in[4];
  const float* W1w = (const float*)d_in[5];
  const float* W1b = (const float*)d_in[6];
  const float* W2w = (const float*)d_in[7];
  const float* W2b = (const float*)d_in[8];
  const float* lng = (const float*)d_in[9];
  const float* lnb = (const float*)d_in[10];

  short* W1f = (short*)d_ws;                         // 131072 B
  short* W2f = W1f + 65536;                          // 32768 B
  unsigned* flag = (unsigned*)((char*)d_ws + 163840);
  float* Z = (float*)((char*)d_ws + 164096);         // 4 MB
  float* U = Z + 1048576;                            // 4 MB
  // ws_size >= 8.6 MB confirmed on this harness (round-5 fast path ran)

  prep1<<<321, 256, 0, stream>>>(W1w, W2w, W1f, W2f, flag);
  prep2<<<640, 256, 0, stream>>>(hS, hV, W1b, W1f, Z, U, (const unsigned*)Ei, flag);
  fusedF<<<2048, 256, 0, stream>>>(hE, Ei, mk, hV, W2b, lng, lnb,
                                   W1f, W2f, Z, U, flag, (float*)d_out);
}